// Round 8
// baseline (881.725 us; speedup 1.0000x reference)
//
#include <hip/hip_runtime.h>
#include <float.h>

// APoT quantizer forward: out = a * nearest_level(clip(x/a, -1, 1)), a = |alpha|+1e-8.
// Reference nearest: ir = clip(searchsorted(levels, xn, 'left'), 0, L-1); il = ir-1 clipped;
//                    choose right iff |xn-left| > |right-xn| (tie -> left).
//
// Fast path (L == 511): levels symmetric -> fold sign, search u=|xn| over the 256
// nonnegative levels P[j] = levels[255+j]. For xn<0 searchsorted-left maps to
// "go right iff e <= u" == "e < nextafter(u)" (one uint add); tie rule flips > to >=.
// Tree over P[1..255]: depths 0..2 in registers (cndmask chains), depths 3..7 in an
// LDS Eytzinger (5 ds_read_b32/elem). a==1.0f (this workload) selects a div-free loop
// (x/1.0 == x bit-exactly). All paths bit-exact vs reference; -0.0 canonicalized.
//
// Ladder (kernel dispatch ~= bench - 2 fills):
//   r0  9-read LDS, NT store:            ~203 us
//   r3  5-read + reg-top, NT store:      ~202 us  (LDS depth: null)
//   r4  + 2x unroll, NT store:           ~207 us  (MLP masked by NT-store cap)
//   r6  5-read, PLAIN store:             ~185 us  (NT store was the bottleneck, -8%)
//   r7  + 2x unroll:                     ~178 us  (MLP live under plain stores, -4%)
// Round-8: 4x unroll (4 outstanding VMEM/wave, 16 chains). Single variable vs r7.
// Pre-commit: bench >= 855 us => r7 is the roofline kernel.

typedef float floatx4 __attribute__((ext_vector_type(4)));

// ---------------- fast path: L == 511 ----------------

template<bool AONE>
__device__ __forceinline__ float apot_fold(
    float xi, float a, const float* __restrict__ eyt, float zl,
    float e1, float e2, float e3, float e4, float e5, float e6, float e7)
{
    float xn = AONE ? xi : (xi / a);            // IEEE div only on generic path
    xn = fminf(fmaxf(xn, -1.0f), 1.0f);
    bool neg = xn < 0.0f;                       // -0.0 takes the positive path
    float u  = fabsf(xn);
    // strict-< with us == (neg ? nextafter(u,+inf) : u) implements e<=u for neg lanes
    float us = __uint_as_float(__float_as_uint(u) + (neg ? 1u : 0u));

    float lft = zl;        // P[0] = 0.0f: left neighbor when nothing smaller passed
    float rgt = FLT_MAX;   // right neighbor when u_s above all levels (only u=1, neg)

    // depth 0..2 in registers
    bool g0 = e1 < us;  lft = g0 ? e1 : lft;  rgt = g0 ? rgt : e1;
    float ea = g0 ? e3 : e2;
    bool g1 = ea < us;  lft = g1 ? ea : lft;  rgt = g1 ? rgt : ea;
    float t0 = g1 ? e5 : e4;
    float t1 = g1 ? e7 : e6;
    float eb = g0 ? t1 : t0;
    bool g2 = eb < us;  lft = g2 ? eb : lft;  rgt = g2 ? rgt : eb;

    // depth 3..7 in LDS
    int idx = 8 + (g0 ? 4 : 0) + (g1 ? 2 : 0) + (g2 ? 1 : 0);
    #pragma unroll
    for (int s = 0; s < 5; ++s) {
        float e = eyt[idx];
        bool g = e < us;
        lft = g ? e : lft;
        rgt = g ? rgt : e;
        idx = 2 * idx + (g ? 1 : 0);
    }

    float dl = u - lft;                          // exact, >= 0 (lft <= u)
    float dr = rgt - u;                          // exact, >= 0 (rgt >= u)
    bool cr = neg ? (dl >= dr) : (dl > dr);      // folded tie rule flips for neg
    float mag = cr ? rgt : lft;
    float res = AONE ? mag : (a * mag);
    res = neg ? -res : res;
    return res + 0.0f;                           // canonicalize -0.0 -> +0.0
}

template<bool AONE>
__device__ __forceinline__ void apot_loop_511(
    const float* __restrict__ x, float* __restrict__ out,
    long long n, long long n4, float a, float zl,
    const float* __restrict__ eyt,
    float e1, float e2, float e3, float e4, float e5, float e6, float e7)
{
    long long tid = (long long)blockIdx.x * blockDim.x + threadIdx.x;
    long long stride = (long long)gridDim.x * blockDim.x;
    const floatx4* __restrict__ x4 = (const floatx4*)x;
    floatx4* __restrict__ o4 = (floatx4*)out;

    long long n16 = n4 >> 2;  // quads of float4 (64 B per lane-iter)
    for (long long t = tid; t < n16; t += stride) {
        // four independent 16B loads issue back-to-back (4 outstanding VMEM/wave)
        floatx4 v0 = x4[4 * t];
        floatx4 v1 = x4[4 * t + 1];
        floatx4 v2 = x4[4 * t + 2];
        floatx4 v3 = x4[4 * t + 3];
        floatx4 o0, o1, o2, o3;
        o0.x = apot_fold<AONE>(v0.x, a, eyt, zl, e1, e2, e3, e4, e5, e6, e7);
        o0.y = apot_fold<AONE>(v0.y, a, eyt, zl, e1, e2, e3, e4, e5, e6, e7);
        o0.z = apot_fold<AONE>(v0.z, a, eyt, zl, e1, e2, e3, e4, e5, e6, e7);
        o0.w = apot_fold<AONE>(v0.w, a, eyt, zl, e1, e2, e3, e4, e5, e6, e7);
        o1.x = apot_fold<AONE>(v1.x, a, eyt, zl, e1, e2, e3, e4, e5, e6, e7);
        o1.y = apot_fold<AONE>(v1.y, a, eyt, zl, e1, e2, e3, e4, e5, e6, e7);
        o1.z = apot_fold<AONE>(v1.z, a, eyt, zl, e1, e2, e3, e4, e5, e6, e7);
        o1.w = apot_fold<AONE>(v1.w, a, eyt, zl, e1, e2, e3, e4, e5, e6, e7);
        o2.x = apot_fold<AONE>(v2.x, a, eyt, zl, e1, e2, e3, e4, e5, e6, e7);
        o2.y = apot_fold<AONE>(v2.y, a, eyt, zl, e1, e2, e3, e4, e5, e6, e7);
        o2.z = apot_fold<AONE>(v2.z, a, eyt, zl, e1, e2, e3, e4, e5, e6, e7);
        o2.w = apot_fold<AONE>(v2.w, a, eyt, zl, e1, e2, e3, e4, e5, e6, e7);
        o3.x = apot_fold<AONE>(v3.x, a, eyt, zl, e1, e2, e3, e4, e5, e6, e7);
        o3.y = apot_fold<AONE>(v3.y, a, eyt, zl, e1, e2, e3, e4, e5, e6, e7);
        o3.z = apot_fold<AONE>(v3.z, a, eyt, zl, e1, e2, e3, e4, e5, e6, e7);
        o3.w = apot_fold<AONE>(v3.w, a, eyt, zl, e1, e2, e3, e4, e5, e6, e7);
        o4[4 * t]     = o0;                      // plain stores (r6-proven)
        o4[4 * t + 1] = o1;
        o4[4 * t + 2] = o2;
        o4[4 * t + 3] = o3;
    }
    // float4 remainder (n4 % 4 != 0) — empty for this shape
    for (long long t = n16 * 4 + tid; t < n4; t += stride) {
        floatx4 v = x4[t];
        floatx4 ov;
        ov.x = apot_fold<AONE>(v.x, a, eyt, zl, e1, e2, e3, e4, e5, e6, e7);
        ov.y = apot_fold<AONE>(v.y, a, eyt, zl, e1, e2, e3, e4, e5, e6, e7);
        ov.z = apot_fold<AONE>(v.z, a, eyt, zl, e1, e2, e3, e4, e5, e6, e7);
        ov.w = apot_fold<AONE>(v.w, a, eyt, zl, e1, e2, e3, e4, e5, e6, e7);
        o4[t] = ov;
    }
    // scalar tail — empty for this shape
    for (long long t = n4 * 4 + tid; t < n; t += stride) {
        out[t] = apot_fold<AONE>(x[t], a, eyt, zl, e1, e2, e3, e4, e5, e6, e7);
    }
}

__global__ __launch_bounds__(256) void apot_kernel_511(
    const float* __restrict__ x,
    const float* __restrict__ alpha,
    const float* __restrict__ levels,
    float* __restrict__ out,
    long long n, long long n4)
{
    // Eytzinger over V[0..254] = P[1..255] = levels[256..510]; nodes 1..255, eyt[0] unused
    __shared__ float eyt[256];
    for (int i = threadIdx.x + 1; i < 256; i += blockDim.x) {
        int d = 31 - __clz(i);                      // depth 0..7
        int pos = i - (1 << d);
        int srt = pos * (1 << (8 - d)) + (1 << (7 - d)) - 1;   // 0..254
        eyt[i] = levels[256 + srt];
    }
    __syncthreads();

    float a  = fabsf(alpha[0]) + 1e-8f;
    float zl = levels[255];                         // +0.0f
    float e1 = eyt[1], e2 = eyt[2], e3 = eyt[3], e4 = eyt[4],
          e5 = eyt[5], e6 = eyt[6], e7 = eyt[7];

    if (a == 1.0f) {   // uniform branch; x/1.0 == x and 1.0*v == v bit-exactly
        apot_loop_511<true >(x, out, n, n4, a, zl, eyt, e1, e2, e3, e4, e5, e6, e7);
    } else {
        apot_loop_511<false>(x, out, n, n4, a, zl, eyt, e1, e2, e3, e4, e5, e6, e7);
    }
}

// ---------------- generic fallback (any L <= 511): round-0 proven kernel ----------------

#define TREE_H 9
#define NNODES (1 << TREE_H)

__device__ __forceinline__ float apot_one(float xi, float a,
                                          const float* __restrict__ eyt,
                                          float lev0, float levmax) {
    float xn = xi / a;
    xn = fminf(fmaxf(xn, -1.0f), 1.0f);
    int idx = 1;
    float lft = lev0;
    float rgt = levmax;
    #pragma unroll
    for (int s = 0; s < TREE_H; ++s) {
        float e = eyt[idx];
        bool go_r = e < xn;
        lft = go_r ? e : lft;
        rgt = go_r ? rgt : e;
        idx = 2 * idx + (go_r ? 1 : 0);
    }
    float d_l = fabsf(xn - lft);
    float d_r = fabsf(rgt - xn);
    return a * ((d_l > d_r) ? rgt : lft);
}

__global__ __launch_bounds__(256) void apot_kernel(
    const float* __restrict__ x,
    const float* __restrict__ alpha,
    const float* __restrict__ levels,
    float* __restrict__ out,
    long long n, long long n4, int L)
{
    __shared__ float eyt[NNODES];
    for (int i = threadIdx.x + 1; i < NNODES; i += blockDim.x) {
        int d = 31 - __clz(i);
        int pos = i - (1 << d);
        int srt = pos * (1 << (TREE_H - d)) + (1 << (TREE_H - 1 - d)) - 1;
        eyt[i] = (srt < L) ? levels[srt] : FLT_MAX;
    }
    __syncthreads();

    float a = fabsf(alpha[0]) + 1e-8f;
    float lev0 = levels[0];
    float levmax = levels[L - 1];

    long long tid = (long long)blockIdx.x * blockDim.x + threadIdx.x;
    long long stride = (long long)gridDim.x * blockDim.x;

    const floatx4* __restrict__ x4 = (const floatx4*)x;
    floatx4* __restrict__ o4 = (floatx4*)out;
    for (long long t = tid; t < n4; t += stride) {
        floatx4 v = x4[t];
        floatx4 ov;
        ov.x = apot_one(v.x, a, eyt, lev0, levmax);
        ov.y = apot_one(v.y, a, eyt, lev0, levmax);
        ov.z = apot_one(v.z, a, eyt, lev0, levmax);
        ov.w = apot_one(v.w, a, eyt, lev0, levmax);
        o4[t] = ov;
    }
    for (long long t = n4 * 4 + tid; t < n; t += stride) {
        out[t] = apot_one(x[t], a, eyt, lev0, levmax);
    }
}

extern "C" void kernel_launch(void* const* d_in, const int* in_sizes, int n_in,
                              void* d_out, int out_size, void* d_ws, size_t ws_size,
                              hipStream_t stream) {
    const float* x      = (const float*)d_in[0];
    const float* alpha  = (const float*)d_in[1];
    const float* levels = (const float*)d_in[2];
    float* out = (float*)d_out;

    long long n  = (long long)out_size;
    long long n4 = n >> 2;
    int L = in_sizes[2];

    const int block = 256;
    long long want = (n4 + block - 1) / block;
    if (want < 1) want = 1;
    int grid = (int)(want < 8192 ? want : 8192);

    if (L == 511) {
        apot_kernel_511<<<grid, block, 0, stream>>>(x, alpha, levels, out, n, n4);
    } else {
        apot_kernel<<<grid, block, 0, stream>>>(x, alpha, levels, out, n, n4, L);
    }
}

// Round 9
// 854.307 us; speedup vs baseline: 1.0321x; 1.0321x over previous
//
#include <hip/hip_runtime.h>
#include <float.h>

// APoT quantizer forward: out = a * nearest_level(clip(x/a, -1, 1)), a = |alpha|+1e-8.
// Reference nearest: ir = clip(searchsorted(levels, xn, 'left'), 0, L-1); il = ir-1 clipped;
//                    choose right iff |xn-left| > |right-xn| (tie -> left).
//
// Fast path (L == 511): levels symmetric -> fold sign, search u=|xn| over the 256
// nonnegative levels P[j] = levels[255+j]. For xn<0 searchsorted-left maps to
// "go right iff e <= u" == "e < nextafter(u)" (one uint add); tie rule flips > to >=.
// Tree over P[1..255]: depths 0..2 in registers (cndmask chains), depths 3..7 in an
// LDS Eytzinger (5 ds_read_b32/elem). a==1.0f (this workload) selects a div-free loop
// (x/1.0 == x bit-exactly). All paths bit-exact vs reference; -0.0 canonicalized.
//
// FINAL ladder (kernel dispatch ~= bench - 2 fills, fills ~338 us x2 untouchable):
//   r0  9-read LDS, NT store:            ~203 us
//   r3  5-read + reg-top, NT store:      ~202 us  (LDS depth: null)
//   r4  + 2x unroll, NT store:           ~207 us  (MLP masked by NT-store cap)
//   r6  5-read, PLAIN store:             ~185 us  (NT store bit cost ~0.5 TB/s: -8%)
//   r7  + 2x unroll:                     ~178 us  (2 outstanding VMEM/wave: -4%)
//   r8  4x unroll:                       ~194 us  (VGPR/occupancy cost > MLP gain)
// r7 = 6.03 TB/s effective = 96% of m13's 6.29 TB/s mixed-stream copy ceiling.
// This file is the r7 kernel, resubmitted as the roofline configuration.

typedef float floatx4 __attribute__((ext_vector_type(4)));

// ---------------- fast path: L == 511 ----------------

template<bool AONE>
__device__ __forceinline__ float apot_fold(
    float xi, float a, const float* __restrict__ eyt, float zl,
    float e1, float e2, float e3, float e4, float e5, float e6, float e7)
{
    float xn = AONE ? xi : (xi / a);            // IEEE div only on generic path
    xn = fminf(fmaxf(xn, -1.0f), 1.0f);
    bool neg = xn < 0.0f;                       // -0.0 takes the positive path
    float u  = fabsf(xn);
    // strict-< with us == (neg ? nextafter(u,+inf) : u) implements e<=u for neg lanes
    float us = __uint_as_float(__float_as_uint(u) + (neg ? 1u : 0u));

    float lft = zl;        // P[0] = 0.0f: left neighbor when nothing smaller passed
    float rgt = FLT_MAX;   // right neighbor when u_s above all levels (only u=1, neg)

    // depth 0..2 in registers
    bool g0 = e1 < us;  lft = g0 ? e1 : lft;  rgt = g0 ? rgt : e1;
    float ea = g0 ? e3 : e2;
    bool g1 = ea < us;  lft = g1 ? ea : lft;  rgt = g1 ? rgt : ea;
    float t0 = g1 ? e5 : e4;
    float t1 = g1 ? e7 : e6;
    float eb = g0 ? t1 : t0;
    bool g2 = eb < us;  lft = g2 ? eb : lft;  rgt = g2 ? rgt : eb;

    // depth 3..7 in LDS
    int idx = 8 + (g0 ? 4 : 0) + (g1 ? 2 : 0) + (g2 ? 1 : 0);
    #pragma unroll
    for (int s = 0; s < 5; ++s) {
        float e = eyt[idx];
        bool g = e < us;
        lft = g ? e : lft;
        rgt = g ? rgt : e;
        idx = 2 * idx + (g ? 1 : 0);
    }

    float dl = u - lft;                          // exact, >= 0 (lft <= u)
    float dr = rgt - u;                          // exact, >= 0 (rgt >= u)
    bool cr = neg ? (dl >= dr) : (dl > dr);      // folded tie rule flips for neg
    float mag = cr ? rgt : lft;
    float res = AONE ? mag : (a * mag);
    res = neg ? -res : res;
    return res + 0.0f;                           // canonicalize -0.0 -> +0.0
}

template<bool AONE>
__device__ __forceinline__ void apot_loop_511(
    const float* __restrict__ x, float* __restrict__ out,
    long long n, long long n4, float a, float zl,
    const float* __restrict__ eyt,
    float e1, float e2, float e3, float e4, float e5, float e6, float e7)
{
    long long tid = (long long)blockIdx.x * blockDim.x + threadIdx.x;
    long long stride = (long long)gridDim.x * blockDim.x;
    const floatx4* __restrict__ x4 = (const floatx4*)x;
    floatx4* __restrict__ o4 = (floatx4*)out;

    long long n8 = n4 >> 1;   // pairs of float4 (32 B per lane-iter)
    for (long long t = tid; t < n8; t += stride) {
        // two independent 16B loads issue back-to-back (2 outstanding VMEM/wave)
        floatx4 v0 = x4[2 * t];
        floatx4 v1 = x4[2 * t + 1];
        floatx4 o0, o1;
        o0.x = apot_fold<AONE>(v0.x, a, eyt, zl, e1, e2, e3, e4, e5, e6, e7);
        o0.y = apot_fold<AONE>(v0.y, a, eyt, zl, e1, e2, e3, e4, e5, e6, e7);
        o0.z = apot_fold<AONE>(v0.z, a, eyt, zl, e1, e2, e3, e4, e5, e6, e7);
        o0.w = apot_fold<AONE>(v0.w, a, eyt, zl, e1, e2, e3, e4, e5, e6, e7);
        o1.x = apot_fold<AONE>(v1.x, a, eyt, zl, e1, e2, e3, e4, e5, e6, e7);
        o1.y = apot_fold<AONE>(v1.y, a, eyt, zl, e1, e2, e3, e4, e5, e6, e7);
        o1.z = apot_fold<AONE>(v1.z, a, eyt, zl, e1, e2, e3, e4, e5, e6, e7);
        o1.w = apot_fold<AONE>(v1.w, a, eyt, zl, e1, e2, e3, e4, e5, e6, e7);
        o4[2 * t]     = o0;                      // plain stores (r6-proven)
        o4[2 * t + 1] = o1;
    }
    // float4 remainder (n4 odd) — empty for this shape
    for (long long t = n8 * 2 + tid; t < n4; t += stride) {
        floatx4 v = x4[t];
        floatx4 ov;
        ov.x = apot_fold<AONE>(v.x, a, eyt, zl, e1, e2, e3, e4, e5, e6, e7);
        ov.y = apot_fold<AONE>(v.y, a, eyt, zl, e1, e2, e3, e4, e5, e6, e7);
        ov.z = apot_fold<AONE>(v.z, a, eyt, zl, e1, e2, e3, e4, e5, e6, e7);
        ov.w = apot_fold<AONE>(v.w, a, eyt, zl, e1, e2, e3, e4, e5, e6, e7);
        o4[t] = ov;
    }
    // scalar tail — empty for this shape
    for (long long t = n4 * 4 + tid; t < n; t += stride) {
        out[t] = apot_fold<AONE>(x[t], a, eyt, zl, e1, e2, e3, e4, e5, e6, e7);
    }
}

__global__ __launch_bounds__(256) void apot_kernel_511(
    const float* __restrict__ x,
    const float* __restrict__ alpha,
    const float* __restrict__ levels,
    float* __restrict__ out,
    long long n, long long n4)
{
    // Eytzinger over V[0..254] = P[1..255] = levels[256..510]; nodes 1..255, eyt[0] unused
    __shared__ float eyt[256];
    for (int i = threadIdx.x + 1; i < 256; i += blockDim.x) {
        int d = 31 - __clz(i);                      // depth 0..7
        int pos = i - (1 << d);
        int srt = pos * (1 << (8 - d)) + (1 << (7 - d)) - 1;   // 0..254
        eyt[i] = levels[256 + srt];
    }
    __syncthreads();

    float a  = fabsf(alpha[0]) + 1e-8f;
    float zl = levels[255];                         // +0.0f
    float e1 = eyt[1], e2 = eyt[2], e3 = eyt[3], e4 = eyt[4],
          e5 = eyt[5], e6 = eyt[6], e7 = eyt[7];

    if (a == 1.0f) {   // uniform branch; x/1.0 == x and 1.0*v == v bit-exactly
        apot_loop_511<true >(x, out, n, n4, a, zl, eyt, e1, e2, e3, e4, e5, e6, e7);
    } else {
        apot_loop_511<false>(x, out, n, n4, a, zl, eyt, e1, e2, e3, e4, e5, e6, e7);
    }
}

// ---------------- generic fallback (any L <= 511): round-0 proven kernel ----------------

#define TREE_H 9
#define NNODES (1 << TREE_H)

__device__ __forceinline__ float apot_one(float xi, float a,
                                          const float* __restrict__ eyt,
                                          float lev0, float levmax) {
    float xn = xi / a;
    xn = fminf(fmaxf(xn, -1.0f), 1.0f);
    int idx = 1;
    float lft = lev0;
    float rgt = levmax;
    #pragma unroll
    for (int s = 0; s < TREE_H; ++s) {
        float e = eyt[idx];
        bool go_r = e < xn;
        lft = go_r ? e : lft;
        rgt = go_r ? rgt : e;
        idx = 2 * idx + (go_r ? 1 : 0);
    }
    float d_l = fabsf(xn - lft);
    float d_r = fabsf(rgt - xn);
    return a * ((d_l > d_r) ? rgt : lft);
}

__global__ __launch_bounds__(256) void apot_kernel(
    const float* __restrict__ x,
    const float* __restrict__ alpha,
    const float* __restrict__ levels,
    float* __restrict__ out,
    long long n, long long n4, int L)
{
    __shared__ float eyt[NNODES];
    for (int i = threadIdx.x + 1; i < NNODES; i += blockDim.x) {
        int d = 31 - __clz(i);
        int pos = i - (1 << d);
        int srt = pos * (1 << (TREE_H - d)) + (1 << (TREE_H - 1 - d)) - 1;
        eyt[i] = (srt < L) ? levels[srt] : FLT_MAX;
    }
    __syncthreads();

    float a = fabsf(alpha[0]) + 1e-8f;
    float lev0 = levels[0];
    float levmax = levels[L - 1];

    long long tid = (long long)blockIdx.x * blockDim.x + threadIdx.x;
    long long stride = (long long)gridDim.x * blockDim.x;

    const floatx4* __restrict__ x4 = (const floatx4*)x;
    floatx4* __restrict__ o4 = (floatx4*)out;
    for (long long t = tid; t < n4; t += stride) {
        floatx4 v = x4[t];
        floatx4 ov;
        ov.x = apot_one(v.x, a, eyt, lev0, levmax);
        ov.y = apot_one(v.y, a, eyt, lev0, levmax);
        ov.z = apot_one(v.z, a, eyt, lev0, levmax);
        ov.w = apot_one(v.w, a, eyt, lev0, levmax);
        o4[t] = ov;
    }
    for (long long t = n4 * 4 + tid; t < n; t += stride) {
        out[t] = apot_one(x[t], a, eyt, lev0, levmax);
    }
}

extern "C" void kernel_launch(void* const* d_in, const int* in_sizes, int n_in,
                              void* d_out, int out_size, void* d_ws, size_t ws_size,
                              hipStream_t stream) {
    const float* x      = (const float*)d_in[0];
    const float* alpha  = (const float*)d_in[1];
    const float* levels = (const float*)d_in[2];
    float* out = (float*)d_out;

    long long n  = (long long)out_size;
    long long n4 = n >> 2;
    int L = in_sizes[2];

    const int block = 256;
    long long want = (n4 + block - 1) / block;
    if (want < 1) want = 1;
    int grid = (int)(want < 8192 ? want : 8192);

    if (L == 511) {
        apot_kernel_511<<<grid, block, 0, stream>>>(x, alpha, levels, out, n, n4);
    } else {
        apot_kernel<<<grid, block, 0, stream>>>(x, alpha, levels, out, n, n4, L);
    }
}